// Round 4
// baseline (495.000 us; speedup 1.0000x reference)
//
#include <hip/hip_runtime.h>

#define NN     2048
#define DIM    512
#define QKS    1024
#define NH     8
#define HD     64
#define NE     32768
#define EPAD   32832
#define CHUNKS 4
#define CH2    8
#define LOG2E  1.4426950408889634f

typedef __attribute__((ext_vector_type(8))) short bf16x8;
typedef __attribute__((ext_vector_type(4))) float f32x4;

#define MFMA(a,b,c) __builtin_amdgcn_mfma_f32_16x16x32_bf16((a),(b),(c),0,0,0)

__device__ __forceinline__ float bf2f(unsigned int u16){
  union { unsigned int i; float f; } v; v.i = u16 << 16; return v.f;
}
__device__ __forceinline__ unsigned short f2bf(float f){
  union { float ff; unsigned int i; } v; v.ff = f;
  return (unsigned short)((v.i + 0x7fffu + ((v.i >> 16) & 1u)) >> 16);
}

// ------- fp32 -> bf16 staging: node_feat -> Xb, edge_feat -> pEF (rows NE.. = 0),
// ------- edge_weight -> pEW (64 rows, rows 40..63 = 0). One 8-elem group/thread.
__global__ __launch_bounds__(256) void cvt_k(
    const float* __restrict__ X, const float* __restrict__ ef, const float* __restrict__ ew,
    unsigned short* __restrict__ Xb, unsigned short* __restrict__ pEF, unsigned short* __restrict__ pEW)
{
  long g = (long)blockIdx.x*256 + threadIdx.x;
  const long GX = (long)NN*DIM/8;                // 131072
  const long GE = (long)EPAD*8;                  // 262656
  const float* src; unsigned short* dst; long off, lim8;
  if (g < GX){ src = X;  dst = Xb;  off = g;        lim8 = GX; }
  else if (g < GX+GE){ src = ef; dst = pEF; off = g-GX; lim8 = (long)NE*8; }
  else { off = g-GX-GE; if (off >= 512) return; src = ew; dst = pEW; lim8 = 320; }
  unsigned short o[8];
  if (off < lim8){
    #pragma unroll
    for (int i=0;i<8;i++) o[i] = f2bf(src[off*8+i]);
  } else {
    #pragma unroll
    for (int i=0;i<8;i++) o[i] = 0;
  }
  *(uint4*)(dst + off*8) = *(const uint4*)o;
}

// ---------------- transpose + convert four 512x512 fp32 weights -> bf16 ----------------
__global__ __launch_bounds__(256) void transpose512(
    const float* __restrict__ a0, const float* __restrict__ a1,
    const float* __restrict__ a2, const float* __restrict__ a3,
    unsigned short* __restrict__ out)
{
  __shared__ unsigned short tile[32][33];
  const float* src = blockIdx.z==0 ? a0 : blockIdx.z==1 ? a1 : blockIdx.z==2 ? a2 : a3;
  unsigned short* dst = out + (size_t)blockIdx.z*DIM*DIM;
  int bx = blockIdx.x*32, by = blockIdx.y*32;
  int tx = threadIdx.x, ty = threadIdx.y;
  #pragma unroll
  for (int i=0;i<32;i+=8) tile[ty+i][tx] = f2bf(src[(size_t)(by+ty+i)*DIM + bx+tx]);
  __syncthreads();
  #pragma unroll
  for (int i=0;i<32;i+=8) dst[(size_t)(bx+ty+i)*DIM + by+tx] = tile[tx][ty+i];
}

// ---------------- generic C[M][N] = A1[M][K] * A2[N][K]^T + bias ----------------
__global__ __launch_bounds__(256) void gemm_bt(
    const unsigned short* __restrict__ A1, const unsigned short* __restrict__ A2,
    const float* __restrict__ biasA, const float* __restrict__ biasB,
    unsigned short* __restrict__ C, float* __restrict__ Cf,
    int M, int N, int K, int bias_row)
{
  int lane = threadIdx.x & 63, w = threadIdx.x >> 6;
  int quad = lane >> 4, low = lane & 15;
  int m0 = blockIdx.y*64 + w*16;
  int n0 = blockIdx.x*64;
  f32x4 acc[4];
  #pragma unroll
  for (int t=0;t<4;t++) acc[t] = (f32x4){0.f,0.f,0.f,0.f};
  for (int k0=0; k0<K; k0+=32){
    bf16x8 a = *(const bf16x8*)(A1 + (size_t)(m0+low)*K + k0 + quad*8);
    #pragma unroll
    for (int t=0;t<4;t++){
      bf16x8 b = *(const bf16x8*)(A2 + (size_t)(n0+16*t+low)*K + k0 + quad*8);
      acc[t] = MFMA(a, b, acc[t]);
    }
  }
  #pragma unroll
  for (int t=0;t<4;t++){
    #pragma unroll
    for (int r=0;r<4;r++){
      int row = m0 + quad*4 + r;
      int col = n0 + 16*t + low;
      float v = acc[t][r];
      if (biasA){
        int bi = bias_row ? row : col;
        v += (bi < 512) ? biasA[bi] : biasB[bi-512];
      }
      if (Cf) Cf[(size_t)row*N + col] = v;
      else    C [(size_t)row*N + col] = f2bf(v);
    }
  }
}

// ---------------- T2 gemm: T[e][l*8+h] = pEF[e]·pEW[l*8+h]; dual layout write ----------------
__global__ __launch_bounds__(256) void t2_k(
    const unsigned short* __restrict__ pEF, const unsigned short* __restrict__ pEW,
    unsigned short* __restrict__ T2, unsigned short* __restrict__ T2L)
{
  int lane = threadIdx.x & 63, w = threadIdx.x >> 6;
  int quad = lane >> 4, low = lane & 15;
  int m0 = blockIdx.y*64 + w*16;
  f32x4 acc[4];
  #pragma unroll
  for (int t=0;t<4;t++) acc[t] = (f32x4){0.f,0.f,0.f,0.f};
  #pragma unroll
  for (int k0=0; k0<64; k0+=32){
    bf16x8 a = *(const bf16x8*)(pEF + (size_t)(m0+low)*64 + k0 + quad*8);
    #pragma unroll
    for (int t=0;t<4;t++){
      bf16x8 b = *(const bf16x8*)(pEW + (size_t)(16*t+low)*64 + k0 + quad*8);
      acc[t] = MFMA(a, b, acc[t]);
    }
  }
  #pragma unroll
  for (int t=0;t<4;t++){
    #pragma unroll
    for (int r=0;r<4;r++){
      int row = m0 + quad*4 + r;
      int col = 16*t + low;
      unsigned short v = f2bf(acc[t][r]);
      T2[(size_t)row*64 + col] = v;
      if (col < 40)
        T2L[((size_t)(col>>3)*EPAD + row)*8 + (col&7)] = v;
    }
  }
}

// ---------------- bias_k: per-pair 8-head bias, barrier-free, 1 thread/pair ----------------
// bias(q,m,h) = sp_table[dist][h] + sum_l T2L[l][sp_l][h]; masked -> -1e30
__global__ __launch_bounds__(256) void bias_k(
    const float* __restrict__ spb, const int* __restrict__ dist,
    const int* __restrict__ sp, const int* __restrict__ maskp,
    const unsigned short* __restrict__ T2L, unsigned short* __restrict__ biasBuf)
{
  int pix = blockIdx.x*256 + threadIdx.x;        // exactly NN*NN threads
  int dd = dist[pix];
  dd = dd < 0 ? 0 : (dd > 5 ? 5 : dd);
  int msk = maskp[pix];
  float b[8];
  #pragma unroll
  for (int x=0;x<8;x++) b[x] = spb[dd*8 + x];
  #pragma unroll
  for (int l=0;l<5;l++){
    int e = sp[(size_t)pix*5 + l];
    if ((unsigned)e > (unsigned)NE) e = NE;
    uint4 tv = *(const uint4*)(T2L + ((size_t)l*EPAD + e)*8);
    b[0] += bf2f(tv.x & 0xffffu); b[1] += bf2f(tv.x >> 16);
    b[2] += bf2f(tv.y & 0xffffu); b[3] += bf2f(tv.y >> 16);
    b[4] += bf2f(tv.z & 0xffffu); b[5] += bf2f(tv.z >> 16);
    b[6] += bf2f(tv.w & 0xffffu); b[7] += bf2f(tv.w >> 16);
  }
  unsigned short o[8];
  #pragma unroll
  for (int x=0;x<8;x++) o[x] = f2bf(msk ? -1e30f : b[x]);
  *(uint4*)(biasBuf + (size_t)pix*8) = *(const uint4*)o;
}

// ---------------- attn2: streams precomputed bias; 3 barriers/tile ----------------
// grid (128, CH2); block 512 = 8 waves, wave h = head h; chunk = 256 m's = 4 tiles.
__global__ __launch_bounds__(512, 8) void attn2_k(
    const unsigned short* __restrict__ Qb, const unsigned short* __restrict__ Kb,
    const unsigned short* __restrict__ Vt, const unsigned short* __restrict__ biasBuf,
    unsigned short* __restrict__ partO)
{
  __shared__ __attribute__((aligned(16))) float sld[NH][16][68];
  int tid = threadIdx.x;
  int lane = tid & 63, h = tid >> 6;
  int quad = lane >> 4, low = lane & 15;
  int q0 = blockIdx.x * 16;
  int chunk = blockIdx.y;

  bf16x8 aq[2];
  #pragma unroll
  for (int s=0;s<2;s++)
    aq[s] = *(const bf16x8*)(Qb + (size_t)(q0+low)*QKS + h*HD + s*32 + quad*8);

  f32x4 accO[4];
  #pragma unroll
  for (int t=0;t<4;t++) accO[t] = (f32x4){0.f,0.f,0.f,0.f};

  uint4 bpf[2];
  #pragma unroll
  for (int it=0; it<2; ++it){
    int p = tid + it*512; int qq = p >> 6, mm = p & 63;
    bpf[it] = *(const uint4*)(biasBuf + ((size_t)(q0+qq)*NN + chunk*256 + mm)*8);
  }

  for (int jt=0; jt<4; ++jt){
    int m0 = chunk*256 + jt*64;
    __syncthreads();   // WAR: previous phase-D readers done

    // ---- phase B (wave h): S = Q K^T * 0.125 -> LDS ----
    f32x4 S[4];
    #pragma unroll
    for (int t=0;t<4;t++) S[t] = (f32x4){0.f,0.f,0.f,0.f};
    #pragma unroll
    for (int s=0;s<2;s++){
      #pragma unroll
      for (int t=0;t<4;t++){
        bf16x8 bk = *(const bf16x8*)(Kb + (size_t)(m0+16*t+low)*QKS + h*HD + s*32 + quad*8);
        S[t] = MFMA(aq[s], bk, S[t]);
      }
    }
    #pragma unroll
    for (int t=0;t<4;t++){
      #pragma unroll
      for (int r=0;r<4;r++)
        sld[h][quad*4+r][low+16*t] = S[t][r]*0.125f;
    }
    __syncthreads();

    // ---- phase C (coop): + bias, softmax over 8 heads per pair ----
    #pragma unroll
    for (int it=0; it<2; ++it){
      int p = tid + it*512;
      int qq = p >> 6, mm = p & 63;
      uint4 bv = bpf[it];
      if (jt < 3)
        bpf[it] = *(const uint4*)(biasBuf + ((size_t)(q0+qq)*NN + m0 + 64 + mm)*8);
      float bb[8];
      bb[0]=bf2f(bv.x & 0xffffu); bb[1]=bf2f(bv.x >> 16);
      bb[2]=bf2f(bv.y & 0xffffu); bb[3]=bf2f(bv.y >> 16);
      bb[4]=bf2f(bv.z & 0xffffu); bb[5]=bf2f(bv.z >> 16);
      bb[6]=bf2f(bv.w & 0xffffu); bb[7]=bf2f(bv.w >> 16);
      float s0[8];
      #pragma unroll
      for (int x=0;x<8;x++) s0[x] = sld[x][qq][mm] + bb[x];
      float mx = s0[0];
      #pragma unroll
      for (int x=1;x<8;x++) mx = fmaxf(mx, s0[x]);
      float sum = 0.f;
      #pragma unroll
      for (int x=0;x<8;x++){ s0[x] = exp2f((s0[x]-mx)*LOG2E); sum += s0[x]; }
      float inv = (mx < -1e29f) ? 0.f : 1.f/sum;
      #pragma unroll
      for (int x=0;x<8;x++) sld[x][qq][mm] = s0[x]*inv;
    }
    __syncthreads();

    // ---- phase D (wave h): O += P V ----
    bf16x8 ap[2];
    #pragma unroll
    for (int s=0;s<2;s++){
      const float* pp = &sld[h][low][s*32 + quad*8];
      float4 x0 = *(const float4*)pp;
      float4 x1 = *(const float4*)(pp + 4);
      bf16x8 a;
      a[0]=(short)f2bf(x0.x); a[1]=(short)f2bf(x0.y); a[2]=(short)f2bf(x0.z); a[3]=(short)f2bf(x0.w);
      a[4]=(short)f2bf(x1.x); a[5]=(short)f2bf(x1.y); a[6]=(short)f2bf(x1.z); a[7]=(short)f2bf(x1.w);
      ap[s] = a;
    }
    #pragma unroll
    for (int s=0;s<2;s++){
      #pragma unroll
      for (int t=0;t<4;t++){
        bf16x8 bv = *(const bf16x8*)(Vt + (size_t)(h*HD + 16*t + low)*NN + m0 + s*32 + quad*8);
        accO[t] = MFMA(ap[s], bv, accO[t]);
      }
    }
  }

  #pragma unroll
  for (int t=0;t<4;t++){
    #pragma unroll
    for (int r=0;r<4;r++){
      int q = quad*4 + r;
      partO[((size_t)chunk*NN + q0 + q)*DIM + h*HD + 16*t + low] = f2bf(accO[t][r]);
    }
  }
}

// ---------------- fallback fused attention (round-3, proven) ----------------
__global__ __launch_bounds__(512) void attn_k(
    const unsigned short* __restrict__ Qb, const unsigned short* __restrict__ Kb,
    const unsigned short* __restrict__ Vt, const unsigned short* __restrict__ T2,
    const float* __restrict__ spb, const int* __restrict__ dist,
    const int* __restrict__ sp, const int* __restrict__ maskp,
    float* __restrict__ partO)
{
  __shared__ __attribute__((aligned(16))) float sld[NH][16][68];
  __shared__ float sptab[48];
  int tid = threadIdx.x;
  int lane = tid & 63, h = tid >> 6;
  int quad = lane >> 4, low = lane & 15;
  int q0 = blockIdx.x * 16;
  int chunk = blockIdx.y;
  if (tid < 48) sptab[tid] = spb[tid];

  bf16x8 aq[2];
  #pragma unroll
  for (int s=0;s<2;s++)
    aq[s] = *(const bf16x8*)(Qb + (size_t)(q0+low)*QKS + h*HD + s*32 + quad*8);

  f32x4 accO[4];
  #pragma unroll
  for (int t=0;t<4;t++) accO[t] = (f32x4){0.f,0.f,0.f,0.f};

  for (int jt=0; jt<8; ++jt){
    int m0 = chunk*512 + jt*64;
    __syncthreads();

    #pragma unroll
    for (int it=0; it<2; ++it){
      int p = tid + it*512;
      int qq = p >> 6, mm = p & 63;
      long pix = (long)(q0+qq)*NN + (m0+mm);
      int dd = dist[pix];
      dd = dd < 0 ? 0 : (dd > 5 ? 5 : dd);
      float b[8];
      #pragma unroll
      for (int x=0;x<8;x++) b[x] = sptab[dd*8 + x];
      #pragma unroll
      for (int l=0;l<5;l++){
        int e = sp[pix*5 + l];
        if ((unsigned)e > (unsigned)NE) e = NE;
        uint4 tv = *(const uint4*)(T2 + (size_t)e*64 + l*8);
        b[0] += bf2f(tv.x & 0xffffu); b[1] += bf2f(tv.x >> 16);
        b[2] += bf2f(tv.y & 0xffffu); b[3] += bf2f(tv.y >> 16);
        b[4] += bf2f(tv.z & 0xffffu); b[5] += bf2f(tv.z >> 16);
        b[6] += bf2f(tv.w & 0xffffu); b[7] += bf2f(tv.w >> 16);
      }
      int msk = maskp[pix];
      #pragma unroll
      for (int x=0;x<8;x++) sld[x][qq][mm] = msk ? -1e30f : b[x];
    }
    __syncthreads();

    f32x4 S[4];
    #pragma unroll
    for (int t=0;t<4;t++) S[t] = (f32x4){0.f,0.f,0.f,0.f};
    #pragma unroll
    for (int s=0;s<2;s++){
      #pragma unroll
      for (int t=0;t<4;t++){
        bf16x8 bk = *(const bf16x8*)(Kb + (size_t)(m0+16*t+low)*QKS + h*HD + s*32 + quad*8);
        S[t] = MFMA(aq[s], bk, S[t]);
      }
    }
    #pragma unroll
    for (int t=0;t<4;t++){
      #pragma unroll
      for (int r=0;r<4;r++){
        float* slot = &sld[h][quad*4+r][low+16*t];
        *slot = S[t][r]*0.125f + *slot;
      }
    }
    __syncthreads();

    #pragma unroll
    for (int it=0; it<2; ++it){
      int p = tid + it*512;
      int qq = p >> 6, mm = p & 63;
      float s0[8];
      #pragma unroll
      for (int x=0;x<8;x++) s0[x] = sld[x][qq][mm];
      float mx = s0[0];
      #pragma unroll
      for (int x=1;x<8;x++) mx = fmaxf(mx, s0[x]);
      float sum = 0.f;
      #pragma unroll
      for (int x=0;x<8;x++){ s0[x] = exp2f((s0[x]-mx)*LOG2E); sum += s0[x]; }
      float inv = (mx < -1e29f) ? 0.f : 1.f/sum;
      #pragma unroll
      for (int x=0;x<8;x++) sld[x][qq][mm] = s0[x]*inv;
    }
    __syncthreads();

    bf16x8 ap[2];
    #pragma unroll
    for (int s=0;s<2;s++){
      const float* pp = &sld[h][low][s*32 + quad*8];
      float4 x0 = *(const float4*)pp;
      float4 x1 = *(const float4*)(pp + 4);
      bf16x8 a;
      a[0]=(short)f2bf(x0.x); a[1]=(short)f2bf(x0.y); a[2]=(short)f2bf(x0.z); a[3]=(short)f2bf(x0.w);
      a[4]=(short)f2bf(x1.x); a[5]=(short)f2bf(x1.y); a[6]=(short)f2bf(x1.z); a[7]=(short)f2bf(x1.w);
      ap[s] = a;
    }
    #pragma unroll
    for (int s=0;s<2;s++){
      #pragma unroll
      for (int t=0;t<4;t++){
        bf16x8 bv = *(const bf16x8*)(Vt + (size_t)(h*HD + 16*t + low)*NN + m0 + s*32 + quad*8);
        accO[t] = MFMA(ap[s], bv, accO[t]);
      }
    }
  }

  #pragma unroll
  for (int t=0;t<4;t++){
    #pragma unroll
    for (int r=0;r<4;r++){
      int q = quad*4 + r;
      partO[((size_t)chunk*NN + q0 + q)*DIM + h*HD + 16*t + low] = accO[t][r];
    }
  }
}

// ---------------- merge partial O's (bf16 or fp32 partials) ----------------
__global__ __launch_bounds__(512) void merge_k(const unsigned short* __restrict__ pb,
                                               const float* __restrict__ pf,
                                               int chunks, unsigned short* __restrict__ Obf)
{
  size_t idx = (size_t)blockIdx.x*512 + threadIdx.x;
  float s = 0.f;
  if (pb){ for (int c=0;c<chunks;c++) s += bf2f(pb[(size_t)c*NN*DIM + idx]); }
  else   { for (int c=0;c<chunks;c++) s += pf[(size_t)c*NN*DIM + idx]; }
  Obf[idx] = f2bf(s);
}

extern "C" void kernel_launch(void* const* d_in, const int* in_sizes, int n_in,
                              void* d_out, int out_size, void* d_ws, size_t ws_size,
                              hipStream_t stream)
{
  const float* X    = (const float*)d_in[0];
  const int*  dist  = (const int*)d_in[3];
  const int*  sp    = (const int*)d_in[4];
  const float* ef   = (const float*)d_in[5];
  const int*  maskp = (const int*)d_in[6];
  const float* WQ   = (const float*)d_in[7];
  const float* bQ   = (const float*)d_in[8];
  const float* WK   = (const float*)d_in[9];
  const float* bK   = (const float*)d_in[10];
  const float* WV   = (const float*)d_in[11];
  const float* bV   = (const float*)d_in[12];
  const float* WO   = (const float*)d_in[13];
  const float* bO   = (const float*)d_in[14];
  const float* spb  = (const float*)d_in[15];
  const float* ew   = (const float*)d_in[16];

  char* ws = (char*)d_ws;
  unsigned short* Wt   = (unsigned short*)(ws + 0);            // 4 x 512x512 bf16 (WQ^T,WK^T,WV^T,WO^T)
  unsigned short* Xb   = (unsigned short*)(ws + 2097152);      // 2048x512 bf16
  unsigned short* QKb  = (unsigned short*)(ws + 4194304);      // 2048x1024 bf16 (Q | K interleaved rows)
  unsigned short* Vtb  = (unsigned short*)(ws + 8388608);      // 512x2048 bf16 (V^T)
  unsigned short* pEF  = (unsigned short*)(ws + 10485760);     // EPAD x 64 bf16
  unsigned short* pEW  = (unsigned short*)(ws + 14688256);     // 64 x 64 bf16
  unsigned short* T2   = (unsigned short*)(ws + 14696448);     // EPAD x 64 bf16 (fallback layout)
  unsigned short* T2L  = (unsigned short*)(ws + 18898944);     // 5 x EPAD x 8 bf16 (plane layout)
  unsigned short* Obf  = (unsigned short*)(ws + 21525504);     // 2048x512 bf16
  char*           pMem = ws + 23622656;                        // partials: 16.8 MB (bf16 x CH2 | f32 x CHUNKS)
  unsigned short* biasBuf = (unsigned short*)(ws + 40399872);  // NN x NN x 8 bf16 = 67.1 MB
  const size_t NEED_BIG = 40399872ULL + 67108864ULL;           // 107.5 MB

  cvt_k<<<dim3(1540), dim3(256), 0, stream>>>(X, ef, ew, Xb, pEF, pEW);
  transpose512<<<dim3(16,16,4), dim3(32,8), 0, stream>>>(WQ, WK, WV, WO, Wt);
  t2_k<<<dim3(1,513), dim3(256), 0, stream>>>(pEF, pEW, T2, T2L);
  // fused Q|K projection: C[2048][1024], B rows = WQ^T (0..511) then WK^T (512..1023)
  gemm_bt<<<dim3(16,32), dim3(256), 0, stream>>>(Xb, Wt, bQ, bK, QKb, (float*)nullptr, NN, QKS, DIM, 0);
  // V^T: rows = dims, cols = nodes
  gemm_bt<<<dim3(32,8), dim3(256), 0, stream>>>(Wt + 524288, Xb, bV, (const float*)nullptr, Vtb, (float*)nullptr, DIM, NN, DIM, 1);

  if (ws_size >= NEED_BIG){
    unsigned short* pObf = (unsigned short*)pMem;
    bias_k<<<dim3(16384), dim3(256), 0, stream>>>(spb, dist, sp, maskp, T2L, biasBuf);
    attn2_k<<<dim3(128,CH2), dim3(512), 0, stream>>>(QKb, QKb + 512, Vtb, biasBuf, pObf);
    merge_k<<<dim3(2048), dim3(512), 0, stream>>>(pObf, (const float*)nullptr, CH2, Obf);
  } else {
    float* pO = (float*)pMem;
    attn_k<<<dim3(128,CHUNKS), dim3(512), 0, stream>>>(QKb, QKb + 512, Vtb, T2, spb, dist, sp, maskp, pO);
    merge_k<<<dim3(2048), dim3(512), 0, stream>>>((const unsigned short*)nullptr, pO, CHUNKS, Obf);
  }

  gemm_bt<<<dim3(8,32), dim3(256), 0, stream>>>(Obf, Wt + 786432, bO, (const float*)nullptr,
                                                (unsigned short*)nullptr, (float*)d_out, NN, DIM, DIM, 0);
}

// Round 6
// 439.463 us; speedup vs baseline: 1.1264x; 1.1264x over previous
//
#include <hip/hip_runtime.h>

#define NN     2048
#define DIM    512
#define QKS    1024
#define NH     8
#define HD     64
#define NE     32768
#define EPAD   32832
#define CH2    8
#define LOG2E  1.4426950408889634f

typedef __attribute__((ext_vector_type(8))) short bf16x8;
typedef __attribute__((ext_vector_type(4))) float f32x4;

#define MFMA(a,b,c) __builtin_amdgcn_mfma_f32_16x16x32_bf16((a),(b),(c),0,0,0)

__device__ __forceinline__ float bf2f(unsigned int u16){
  union { unsigned int i; float f; } v; v.i = u16 << 16; return v.f;
}
__device__ __forceinline__ unsigned short f2bf(float f){
  union { float ff; unsigned int i; } v; v.ff = f;
  return (unsigned short)((v.i + 0x7fffu + ((v.i >> 16) & 1u)) >> 16);
}

// ------- fp32 -> bf16 staging: node_feat -> Xb, edge_feat -> pEF (rows NE.. = 0),
// ------- edge_weight -> pEW (64 rows, rows 40..63 = 0). One 8-elem group/thread.
__global__ __launch_bounds__(256) void cvt_k(
    const float* __restrict__ X, const float* __restrict__ ef, const float* __restrict__ ew,
    unsigned short* __restrict__ Xb, unsigned short* __restrict__ pEF, unsigned short* __restrict__ pEW)
{
  long g = (long)blockIdx.x*256 + threadIdx.x;
  const long GX = (long)NN*DIM/8;                // 131072
  const long GE = (long)EPAD*8;                  // 262656
  const float* src; unsigned short* dst; long off, lim8;
  if (g < GX){ src = X;  dst = Xb;  off = g;        lim8 = GX; }
  else if (g < GX+GE){ src = ef; dst = pEF; off = g-GX; lim8 = (long)NE*8; }
  else { off = g-GX-GE; if (off >= 512) return; src = ew; dst = pEW; lim8 = 320; }
  unsigned short o[8];
  if (off < lim8){
    #pragma unroll
    for (int i=0;i<8;i++) o[i] = f2bf(src[off*8+i]);
  } else {
    #pragma unroll
    for (int i=0;i<8;i++) o[i] = 0;
  }
  *(uint4*)(dst + off*8) = *(const uint4*)o;
}

// ---------------- transpose + convert four 512x512 fp32 weights -> bf16 ----------------
__global__ __launch_bounds__(256) void transpose512(
    const float* __restrict__ a0, const float* __restrict__ a1,
    const float* __restrict__ a2, const float* __restrict__ a3,
    unsigned short* __restrict__ out)
{
  __shared__ unsigned short tile[32][33];
  const float* src = blockIdx.z==0 ? a0 : blockIdx.z==1 ? a1 : blockIdx.z==2 ? a2 : a3;
  unsigned short* dst = out + (size_t)blockIdx.z*DIM*DIM;
  int bx = blockIdx.x*32, by = blockIdx.y*32;
  int tx = threadIdx.x, ty = threadIdx.y;
  #pragma unroll
  for (int i=0;i<32;i+=8) tile[ty+i][tx] = f2bf(src[(size_t)(by+ty+i)*DIM + bx+tx]);
  __syncthreads();
  #pragma unroll
  for (int i=0;i<32;i+=8) dst[(size_t)(bx+ty+i)*DIM + by+tx] = tile[tx][ty+i];
}

// ---------------- generic C[M][N] = A1[M][K] * A2[N][K]^T + bias ----------------
__global__ __launch_bounds__(256) void gemm_bt(
    const unsigned short* __restrict__ A1, const unsigned short* __restrict__ A2,
    const float* __restrict__ biasA, const float* __restrict__ biasB,
    unsigned short* __restrict__ C, float* __restrict__ Cf,
    int M, int N, int K, int bias_row)
{
  int lane = threadIdx.x & 63, w = threadIdx.x >> 6;
  int quad = lane >> 4, low = lane & 15;
  int m0 = blockIdx.y*64 + w*16;
  int n0 = blockIdx.x*64;
  f32x4 acc[4];
  #pragma unroll
  for (int t=0;t<4;t++) acc[t] = (f32x4){0.f,0.f,0.f,0.f};
  for (int k0=0; k0<K; k0+=32){
    bf16x8 a = *(const bf16x8*)(A1 + (size_t)(m0+low)*K + k0 + quad*8);
    #pragma unroll
    for (int t=0;t<4;t++){
      bf16x8 b = *(const bf16x8*)(A2 + (size_t)(n0+16*t+low)*K + k0 + quad*8);
      acc[t] = MFMA(a, b, acc[t]);
    }
  }
  #pragma unroll
  for (int t=0;t<4;t++){
    #pragma unroll
    for (int r=0;r<4;r++){
      int row = m0 + quad*4 + r;
      int col = n0 + 16*t + low;
      float v = acc[t][r];
      if (biasA){
        int bi = bias_row ? row : col;
        v += (bi < 512) ? biasA[bi] : biasB[bi-512];
      }
      if (Cf) Cf[(size_t)row*N + col] = v;
      else    C [(size_t)row*N + col] = f2bf(v);
    }
  }
}

// ---------------- T2L gemm: T2L[l][e][h] = pEF[e]·pEW[l*8+h] ----------------
// covers e in [0, EPAD); rows >= NE are zero (pEF zero-padded) including e = NE sentinel.
__global__ __launch_bounds__(256) void t2_k(
    const unsigned short* __restrict__ pEF, const unsigned short* __restrict__ pEW,
    unsigned short* __restrict__ T2L)
{
  int lane = threadIdx.x & 63, w = threadIdx.x >> 6;
  int quad = lane >> 4, low = lane & 15;
  int m0 = blockIdx.y*64 + w*16;
  f32x4 acc[4];
  #pragma unroll
  for (int t=0;t<4;t++) acc[t] = (f32x4){0.f,0.f,0.f,0.f};
  #pragma unroll
  for (int k0=0; k0<64; k0+=32){
    bf16x8 a = *(const bf16x8*)(pEF + (size_t)(m0+low)*64 + k0 + quad*8);
    #pragma unroll
    for (int t=0;t<4;t++){
      bf16x8 b = *(const bf16x8*)(pEW + (size_t)(16*t+low)*64 + k0 + quad*8);
      acc[t] = MFMA(a, b, acc[t]);
    }
  }
  #pragma unroll
  for (int t=0;t<4;t++){
    #pragma unroll
    for (int r=0;r<4;r++){
      int row = m0 + quad*4 + r;
      int col = 16*t + low;
      if (col < 40)
        T2L[((size_t)(col>>3)*EPAD + row)*8 + (col&7)] = f2bf(acc[t][r]);
    }
  }
}

// ================= bias_k: per-pair 8-head bias; all 5 gathers issued before use =================
__global__ __launch_bounds__(256) void bias_k(
    const float* __restrict__ spb, const int* __restrict__ dist,
    const int* __restrict__ sp, const int* __restrict__ maskp,
    const unsigned short* __restrict__ T2L, unsigned short* __restrict__ biasBuf)
{
  int pix = blockIdx.x*256 + threadIdx.x;        // exactly NN*NN threads
  int dd = dist[pix];
  int msk = maskp[pix];
  const int* spp = sp + (size_t)pix*5;
  int e0 = spp[0], e1 = spp[1], e2 = spp[2], e3 = spp[3], e4 = spp[4];
  if ((unsigned)e0 > (unsigned)NE) e0 = NE;
  if ((unsigned)e1 > (unsigned)NE) e1 = NE;
  if ((unsigned)e2 > (unsigned)NE) e2 = NE;
  if ((unsigned)e3 > (unsigned)NE) e3 = NE;
  if ((unsigned)e4 > (unsigned)NE) e4 = NE;
  // issue all five 16B gathers before consuming any result (ILP over L2 latency)
  uint4 t0 = *(const uint4*)(T2L + ((size_t)0*EPAD + e0)*8);
  uint4 t1 = *(const uint4*)(T2L + ((size_t)1*EPAD + e1)*8);
  uint4 t2 = *(const uint4*)(T2L + ((size_t)2*EPAD + e2)*8);
  uint4 t3 = *(const uint4*)(T2L + ((size_t)3*EPAD + e3)*8);
  uint4 t4 = *(const uint4*)(T2L + ((size_t)4*EPAD + e4)*8);
  dd = dd < 0 ? 0 : (dd > 5 ? 5 : dd);
  float b[8];
  #pragma unroll
  for (int x=0;x<8;x++) b[x] = spb[dd*8 + x];
  b[0] += bf2f(t0.x & 0xffffu) + bf2f(t1.x & 0xffffu) + bf2f(t2.x & 0xffffu) + bf2f(t3.x & 0xffffu) + bf2f(t4.x & 0xffffu);
  b[1] += bf2f(t0.x >> 16)     + bf2f(t1.x >> 16)     + bf2f(t2.x >> 16)     + bf2f(t3.x >> 16)     + bf2f(t4.x >> 16);
  b[2] += bf2f(t0.y & 0xffffu) + bf2f(t1.y & 0xffffu) + bf2f(t2.y & 0xffffu) + bf2f(t3.y & 0xffffu) + bf2f(t4.y & 0xffffu);
  b[3] += bf2f(t0.y >> 16)     + bf2f(t1.y >> 16)     + bf2f(t2.y >> 16)     + bf2f(t3.y >> 16)     + bf2f(t4.y >> 16);
  b[4] += bf2f(t0.z & 0xffffu) + bf2f(t1.z & 0xffffu) + bf2f(t2.z & 0xffffu) + bf2f(t3.z & 0xffffu) + bf2f(t4.z & 0xffffu);
  b[5] += bf2f(t0.z >> 16)     + bf2f(t1.z >> 16)     + bf2f(t2.z >> 16)     + bf2f(t3.z >> 16)     + bf2f(t4.z >> 16);
  b[6] += bf2f(t0.w & 0xffffu) + bf2f(t1.w & 0xffffu) + bf2f(t2.w & 0xffffu) + bf2f(t3.w & 0xffffu) + bf2f(t4.w & 0xffffu);
  b[7] += bf2f(t0.w >> 16)     + bf2f(t1.w >> 16)     + bf2f(t2.w >> 16)     + bf2f(t3.w >> 16)     + bf2f(t4.w >> 16);
  unsigned short o[8];
  #pragma unroll
  for (int x=0;x<8;x++) o[x] = f2bf(msk ? -1e30f : b[x]);
  *(uint4*)(biasBuf + (size_t)pix*8) = *(const uint4*)o;
}

// ================= attn2: streams precomputed bias; bf16 score/P LDS =================
// grid (128, CH2); block 512 = 8 waves, wave h = head h; chunk = 256 m = 4 tiles.
// Softmax is over HEADS per (q,m) pair (reference: softmax axis=-1 on (n,m,h)).
__global__ __launch_bounds__(512) void attn2_k(
    const unsigned short* __restrict__ Qb, const unsigned short* __restrict__ Kb,
    const unsigned short* __restrict__ Vt, const unsigned short* __restrict__ biasBuf,
    unsigned short* __restrict__ partO)
{
  __shared__ __attribute__((aligned(16))) unsigned short sldb[NH][16][72];  // 18.4 KB, row=144B
  int tid = threadIdx.x;
  int lane = tid & 63, h = tid >> 6;
  int quad = lane >> 4, low = lane & 15;
  int q0 = blockIdx.x * 16;
  int chunk = blockIdx.y;

  bf16x8 aq[2];
  #pragma unroll
  for (int s=0;s<2;s++)
    aq[s] = *(const bf16x8*)(Qb + (size_t)(q0+low)*QKS + h*HD + s*32 + quad*8);

  f32x4 accO[4];
  #pragma unroll
  for (int t=0;t<4;t++) accO[t] = (f32x4){0.f,0.f,0.f,0.f};

  uint4 bpf[2];
  #pragma unroll
  for (int it=0; it<2; ++it){
    int p = tid + it*512; int qq = p >> 6, mm = p & 63;
    bpf[it] = *(const uint4*)(biasBuf + ((size_t)(q0+qq)*NN + chunk*256 + mm)*8);
  }

  for (int jt=0; jt<4; ++jt){
    int m0 = chunk*256 + jt*64;
    __syncthreads();   // WAR: previous phase-D readers done

    // ---- phase B (wave h): S = Q K^T * 0.125 -> bf16 LDS ----
    f32x4 S[4];
    #pragma unroll
    for (int t=0;t<4;t++) S[t] = (f32x4){0.f,0.f,0.f,0.f};
    #pragma unroll
    for (int s=0;s<2;s++){
      #pragma unroll
      for (int t=0;t<4;t++){
        bf16x8 bk = *(const bf16x8*)(Kb + (size_t)(m0+16*t+low)*QKS + h*HD + s*32 + quad*8);
        S[t] = MFMA(aq[s], bk, S[t]);
      }
    }
    #pragma unroll
    for (int t=0;t<4;t++){
      #pragma unroll
      for (int r=0;r<4;r++)
        sldb[h][quad*4+r][low+16*t] = f2bf(S[t][r]*0.125f);
    }
    __syncthreads();

    // ---- phase C (coop): + bias, softmax over 8 heads per pair, P -> bf16 LDS ----
    #pragma unroll
    for (int it=0; it<2; ++it){
      int p = tid + it*512;
      int qq = p >> 6, mm = p & 63;
      uint4 bv = bpf[it];
      if (jt < 3)
        bpf[it] = *(const uint4*)(biasBuf + ((size_t)(q0+qq)*NN + m0 + 64 + mm)*8);
      float s0[8];
      s0[0] = bf2f(sldb[0][qq][mm]) + bf2f(bv.x & 0xffffu);
      s0[1] = bf2f(sldb[1][qq][mm]) + bf2f(bv.x >> 16);
      s0[2] = bf2f(sldb[2][qq][mm]) + bf2f(bv.y & 0xffffu);
      s0[3] = bf2f(sldb[3][qq][mm]) + bf2f(bv.y >> 16);
      s0[4] = bf2f(sldb[4][qq][mm]) + bf2f(bv.z & 0xffffu);
      s0[5] = bf2f(sldb[5][qq][mm]) + bf2f(bv.z >> 16);
      s0[6] = bf2f(sldb[6][qq][mm]) + bf2f(bv.w & 0xffffu);
      s0[7] = bf2f(sldb[7][qq][mm]) + bf2f(bv.w >> 16);
      float mx = s0[0];
      #pragma unroll
      for (int x=1;x<8;x++) mx = fmaxf(mx, s0[x]);
      float sum = 0.f;
      #pragma unroll
      for (int x=0;x<8;x++){ s0[x] = exp2f((s0[x]-mx)*LOG2E); sum += s0[x]; }
      float inv = (mx < -1e29f) ? 0.f : 1.f/sum;
      #pragma unroll
      for (int x=0;x<8;x++) sldb[x][qq][mm] = f2bf(s0[x]*inv);
    }
    __syncthreads();

    // ---- phase D (wave h): O += P V ; A-frags read directly as bf16x8 from LDS ----
    #pragma unroll
    for (int s=0;s<2;s++){
      bf16x8 ap = *(const bf16x8*)&sldb[h][low][s*32 + quad*8];
      #pragma unroll
      for (int t=0;t<4;t++){
        bf16x8 bv = *(const bf16x8*)(Vt + (size_t)(h*HD + 16*t + low)*NN + m0 + s*32 + quad*8);
        accO[t] = MFMA(ap, bv, accO[t]);
      }
    }
  }

  #pragma unroll
  for (int t=0;t<4;t++){
    #pragma unroll
    for (int r=0;r<4;r++){
      int q = quad*4 + r;
      partO[((size_t)chunk*NN + q0 + q)*DIM + h*HD + 16*t + low] = f2bf(accO[t][r]);
    }
  }
}

// ---------------- merge CH2 bf16 partials -> Obf ----------------
__global__ __launch_bounds__(512) void merge_k(const unsigned short* __restrict__ pb,
                                               unsigned short* __restrict__ Obf)
{
  size_t idx = (size_t)blockIdx.x*512 + threadIdx.x;
  float s = 0.f;
  #pragma unroll
  for (int c=0;c<CH2;c++) s += bf2f(pb[(size_t)c*NN*DIM + idx]);
  Obf[idx] = f2bf(s);
}

extern "C" void kernel_launch(void* const* d_in, const int* in_sizes, int n_in,
                              void* d_out, int out_size, void* d_ws, size_t ws_size,
                              hipStream_t stream)
{
  const float* X    = (const float*)d_in[0];
  const int*  dist  = (const int*)d_in[3];
  const int*  sp    = (const int*)d_in[4];
  const float* ef   = (const float*)d_in[5];
  const int*  maskp = (const int*)d_in[6];
  const float* WQ   = (const float*)d_in[7];
  const float* bQ   = (const float*)d_in[8];
  const float* WK   = (const float*)d_in[9];
  const float* bK   = (const float*)d_in[10];
  const float* WV   = (const float*)d_in[11];
  const float* bV   = (const float*)d_in[12];
  const float* WO   = (const float*)d_in[13];
  const float* bO   = (const float*)d_in[14];
  const float* spb  = (const float*)d_in[15];
  const float* ew   = (const float*)d_in[16];

  char* ws = (char*)d_ws;
  unsigned short* Wt      = (unsigned short*)(ws + 0);         // 4 x 512x512 bf16 (WQ^T,WK^T,WV^T,WO^T)
  unsigned short* Xb      = (unsigned short*)(ws + 2097152);   // 2048x512 bf16
  unsigned short* QKb     = (unsigned short*)(ws + 4194304);   // 2048x1024 bf16 (Q|K)
  unsigned short* Vtb     = (unsigned short*)(ws + 8388608);   // 512x2048 bf16 (V^T)
  unsigned short* pEF     = (unsigned short*)(ws + 10485760);  // EPAD x 64 bf16
  unsigned short* pEW     = (unsigned short*)(ws + 14688256);  // 64 x 64 bf16
  unsigned short* T2L     = (unsigned short*)(ws + 14696448);  // 5 x EPAD x 8 bf16 (2.6 MB)
  unsigned short* Obf     = (unsigned short*)(ws + 17323008);  // 2048x512 bf16
  unsigned short* partO   = (unsigned short*)(ws + 19420160);  // CH2 x 2048x512 bf16 (16.8 MB)
  unsigned short* biasBuf = (unsigned short*)(ws + 36197376);  // NN x NN x 8 bf16 (67.1 MB); total 98.5 MB

  cvt_k<<<dim3(1540), dim3(256), 0, stream>>>(X, ef, ew, Xb, pEF, pEW);
  transpose512<<<dim3(16,16,4), dim3(32,8), 0, stream>>>(WQ, WK, WV, WO, Wt);
  t2_k<<<dim3(1,513), dim3(256), 0, stream>>>(pEF, pEW, T2L);
  // fused Q|K projection: C[2048][1024], B rows = WQ^T (0..511) then WK^T (512..1023)
  gemm_bt<<<dim3(16,32), dim3(256), 0, stream>>>(Xb, Wt, bQ, bK, QKb, (float*)nullptr, NN, QKS, DIM, 0);
  // V^T: rows = dims, cols = nodes
  gemm_bt<<<dim3(32,8), dim3(256), 0, stream>>>(Wt + 524288, Xb, bV, (const float*)nullptr, Vtb, (float*)nullptr, DIM, NN, DIM, 1);
  bias_k<<<dim3(16384), dim3(256), 0, stream>>>(spb, dist, sp, maskp, T2L, biasBuf);
  attn2_k<<<dim3(128,CH2), dim3(512), 0, stream>>>(QKb, QKb + 512, Vtb, biasBuf, partO);
  merge_k<<<dim3(2048), dim3(512), 0, stream>>>(partO, Obf);
  gemm_bt<<<dim3(8,32), dim3(256), 0, stream>>>(Obf, Wt + 786432, bO, (const float*)nullptr,
                                                (unsigned short*)nullptr, (float*)d_out, NN, DIM, DIM, 0);
}